// Round 20
// baseline (197.434 us; speedup 1.0000x reference)
//
#include <hip/hip_runtime.h>
#include <math.h>

#define Bn 128
#define Sn 200
#define NC3n 4000
#define GRUB 64                 // 64 GRU blocks x 2 rows (shared role waves)
#define FILLB (Bn * 3)          // 384 fill blocks, (b, t-third)

typedef float vf4 __attribute__((ext_vector_type(4)));

__device__ __forceinline__ float fexp(float x) { return __builtin_amdgcn_exp2f(x * 1.44269504f); }
__device__ __forceinline__ float frcp(float x) { return __builtin_amdgcn_rcpf(x); }
__device__ __forceinline__ float fsig(float x) { return frcp(1.f + fexp(-x)); }
__device__ __forceinline__ float rlanef(float v, int k) {
    return __int_as_float(__builtin_amdgcn_readlane(__float_as_int(v), k));
}
__device__ __forceinline__ void nt_store4(float* p, float4 q) {
    vf4 v; v.x = q.x; v.y = q.y; v.z = q.z; v.w = q.w;
    __builtin_nontemporal_store(v, (vf4*)p);
}
__device__ __forceinline__ void lds_barrier() {
    __builtin_amdgcn_sched_barrier(0);
    asm volatile("s_waitcnt lgkmcnt(0)" ::: "memory");
    __builtin_amdgcn_s_barrier();
    __builtin_amdgcn_sched_barrier(0);
}
__device__ __forceinline__ unsigned short f2bf(float f) {   // RNE f32->bf16
    unsigned u = __float_as_uint(f);
    return (unsigned short)((u + 0x7FFFu + ((u >> 16) & 1u)) >> 16);
}

#define UPD(q, cbase) { int d = cc - (cbase); if ((unsigned)d < 4u) { \
    q.x = (d==0)?v:q.x; q.y = (d==1)?v:q.y; q.z = (d==2)?v:q.z; q.w = (d==3)?v:q.w; } }

struct GruLds {                 // 64,896 B
    float hbc[2][4][64];        // per-row per-wave h broadcast strips (2048)
    float u[192], w0[192], w1[192];         // folded xg (2304)
    float hg[2][2][192];        // [rw][buf] ping-pong W_hh@h + b_hh (6144)
    float gam[2][Sn];           // (1600)
    int   r[2][Sn];             // (1600)
    unsigned short pPart[2][Sn][64];        // bf16 mlp1 partials (51200)
};
struct FillLds {                // ~6.2 KB
    float gam[Sn], val[Sn];
    int   r[Sn], c3[Sn], succ[Sn], root[Sn];
    float A[64], Bv[64], C0[64], C1[64], W2[64];
    float l2b2;
};

__global__ __launch_bounds__(256, 2) void fused12_kernel(
    const int* __restrict__ c3_seq, const int* __restrict__ d_seq,
    const int* __restrict__ r_seq, const float* __restrict__ v_c3,
    const float* __restrict__ D_w, const float* __restrict__ v_d,
    const float* __restrict__ R_w, const float* __restrict__ W_ih,
    const float* __restrict__ W_hh, const float* __restrict__ b_ih,
    const float* __restrict__ b_hh,
    const float* __restrict__ l1_w1, const float* __restrict__ l1_b1,
    const float* __restrict__ l1_w2, const float* __restrict__ l1_b2,
    const float* __restrict__ l2_w1, const float* __restrict__ l2_b1,
    const float* __restrict__ l2_w2, const float* __restrict__ l2_b2,
    float* __restrict__ out_alpha, float* __restrict__ out_h,
    float* __restrict__ out_c3)
{
    __shared__ __align__(16) union { GruLds g; FillLds f; } S;

    const int tid = threadIdx.x;
    const int bid = blockIdx.x;

    if (bid < GRUB) {
        // ===== GRU x2 rows: 4 role waves serve BOTH rows (shared weights),
        // 1 LDS-only barrier per step covers 2 independent recurrences =====
        __builtin_amdgcn_s_setprio(1);
        const int role = tid >> 6;          // 0=r,1=z,2=n,3=mlp1
        const int j    = tid & 63;

        for (int i = tid; i < 2 * Sn; i += 256) {
            int rw2 = (i >= Sn) ? 1 : 0;
            int t2  = i - rw2 * Sn;
            int bb  = bid * 2 + rw2;
            S.g.gam[rw2][t2] = D_w[d_seq[bb * Sn + t2]];
            S.g.r[rw2][t2]   = r_seq[bb * Sn + t2];
        }
        // fold xg (row-independent): u = W_ih[:, :64]@v_d ; w0/w1 = W_ih[:,64:]@R_w[r] + b_ih
        if (tid < 192) {
            const float4* rp  = (const float4*)(W_ih + (size_t)tid * 128);
            const float4* vd4 = (const float4*)v_d;
            const float4* q04 = (const float4*)R_w;
            const float4* q14 = (const float4*)(R_w + 64);
            float u = 0.f, w0 = 0.f, w1 = 0.f;
            #pragma unroll 4
            for (int k = 0; k < 16; ++k) {
                float4 a  = rp[k];
                float4 bb = rp[16 + k];
                float4 vd = vd4[k], q0 = q04[k], q1 = q14[k];
                u  += a.x*vd.x + a.y*vd.y + a.z*vd.z + a.w*vd.w;
                w0 += bb.x*q0.x + bb.y*q0.y + bb.z*q0.z + bb.w*q0.w;
                w1 += bb.x*q1.x + bb.y*q1.y + bb.z*q1.z + bb.w*q1.w;
            }
            float bih = b_ih[tid];
            S.g.u[tid]  = u;
            S.g.w0[tid] = w0 + bih;
            S.g.w1[tid] = w1 + bih;
        }
        // per-wave weight row (shared by both batch rows)
        float w[64];
        {
            const float* src = (role < 3) ? (W_hh + (size_t)(role * 64 + j) * 64)
                                          : (l1_w1 + (size_t)j * 64);
            const float4* s4 = (const float4*)src;
            #pragma unroll
            for (int k = 0; k < 16; ++k) {
                float4 v = s4[k];
                w[4*k+0]=v.x; w[4*k+1]=v.y; w[4*k+2]=v.z; w[4*k+3]=v.w;
            }
        }
        #pragma unroll
        for (int k = 0; k < 16; ++k)
            asm volatile("" : "+v"(w[4*k+0]), "+v"(w[4*k+1]), "+v"(w[4*k+2]), "+v"(w[4*k+3]));

        float bown = 0.f, l1b = 0.f, l1w2v = 0.f;
        if (role < 3) {
            bown = b_hh[role * 64 + j];
            S.g.hg[0][0][role * 64 + j] = bown;   // h0=0 -> hg(t=0)=b_hh (both rows)
            S.g.hg[1][0][role * 64 + j] = bown;
        } else {
            l1b = l1_b1[j]; l1w2v = l1_w2[j];
        }
        const float l1b2c = l1_b2[0];
        __syncthreads();

        const float uj  = S.g.u[j],  u1  = S.g.u[64+j],  u2  = S.g.u[128+j];
        const float w00 = S.g.w0[j], w01 = S.g.w0[64+j], w02 = S.g.w0[128+j];
        const float w10 = S.g.w1[j], w11 = S.g.w1[64+j], w12 = S.g.w1[128+j];

        float vh0 = 0.f, vh1 = 0.f;
        float* outp = out_h + (size_t)(bid * 2 + ((role == 1) ? 1 : 0)) * Sn * 64 + j;
        float gamc0 = S.g.gam[0][0], gamc1 = S.g.gam[1][0];
        int   rc0   = S.g.r[0][0],   rc1   = S.g.r[1][0];

        for (int t = 0; t < Sn; ++t) {
            const int buf = t & 1;
            // critical deps first: 6 hg reads (both rows)
            float hr0 = S.g.hg[0][buf][j], hz0 = S.g.hg[0][buf][64+j], hn0 = S.g.hg[0][buf][128+j];
            float hr1 = S.g.hg[1][buf][j], hz1 = S.g.hg[1][buf][64+j], hn1 = S.g.hg[1][buf][128+j];
            // row0 gates
            float rg0 = fsig(fmaf(gamc0, uj, rc0 ? w10 : w00) + hr0);
            float zg0 = fsig(fmaf(gamc0, u1, rc0 ? w11 : w01) + hz0);
            float e20 = fexp(2.f * (fmaf(gamc0, u2, rc0 ? w12 : w02) + rg0 * hn0));
            float ng0 = 1.f - 2.f * frcp(e20 + 1.f);
            vh0 = (1.f - zg0) * ng0 + zg0 * vh0;
            // row1 gates (independent chain — interleaves with row0)
            float rg1 = fsig(fmaf(gamc1, uj, rc1 ? w10 : w00) + hr1);
            float zg1 = fsig(fmaf(gamc1, u1, rc1 ? w11 : w01) + hz1);
            float e21 = fexp(2.f * (fmaf(gamc1, u2, rc1 ? w12 : w02) + rg1 * hn1));
            float ng1 = 1.f - 2.f * frcp(e21 + 1.f);
            vh1 = (1.f - zg1) * ng1 + zg1 * vh1;
            // broadcast both rows' h
            S.g.hbc[0][role][j] = vh0;
            S.g.hbc[1][role][j] = vh1;
            if (role == 0) { outp[0] = vh0; outp += 64; }       // fire-and-forget
            if (role == 1) { outp[0] = vh1; outp += 64; }
            float4 h0[16], h1[16];
            #pragma unroll
            for (int k = 0; k < 16; ++k) h0[k] = *(const float4*)&S.g.hbc[0][role][k * 4];
            #pragma unroll
            for (int k = 0; k < 16; ++k) h1[k] = *(const float4*)&S.g.hbc[1][role][k * 4];
            __builtin_amdgcn_sched_barrier(0);
            if (t + 1 < Sn) {
                gamc0 = S.g.gam[0][t + 1]; rc0 = S.g.r[0][t + 1];
                gamc1 = S.g.gam[1][t + 1]; rc1 = S.g.r[1][t + 1];
            }
            float a0=0.f, a1=0.f, a2=0.f, a3=0.f;
            float b0=0.f, b1=0.f, b2=0.f, b3=0.f;
            #pragma unroll
            for (int k = 0; k < 16; ++k) {
                a0 = fmaf(w[4*k+0], h0[k].x, a0); a1 = fmaf(w[4*k+1], h0[k].y, a1);
                a2 = fmaf(w[4*k+2], h0[k].z, a2); a3 = fmaf(w[4*k+3], h0[k].w, a3);
                b0 = fmaf(w[4*k+0], h1[k].x, b0); b1 = fmaf(w[4*k+1], h1[k].y, b1);
                b2 = fmaf(w[4*k+2], h1[k].z, b2); b3 = fmaf(w[4*k+3], h1[k].w, b3);
            }
            float dot0 = (a0 + a1) + (a2 + a3);
            float dot1 = (b0 + b1) + (b2 + b3);
            if (role < 3) {
                S.g.hg[0][buf ^ 1][role * 64 + j] = bown + dot0;
                S.g.hg[1][buf ^ 1][role * 64 + j] = bown + dot1;
            } else {
                S.g.pPart[0][t][j] = f2bf(fmaxf(dot0 + l1b, 0.f) * l1w2v);
                S.g.pPart[1][t][j] = f2bf(fmaxf(dot1 + l1b, 0.f) * l1w2v);
            }
            lds_barrier();
        }
        // deferred mlp1 sums + alpha chains: role3 -> row0, role2 -> row1
        if (role >= 2) {
            const int rw = (role == 3) ? 0 : 1;
            const int b  = bid * 2 + rw;
            const int j3 = (j < 8) ? (192 + j) : 199;
            const int ts0 = j, ts1 = 64 + j, ts2 = 128 + j, ts3 = j3;
            float an[4];
            int tss[4] = {ts0, ts1, ts2, ts3};
            #pragma unroll
            for (int q = 0; q < 4; ++q) {
                const uint4* pp = (const uint4*)&S.g.pPart[rw][tss[q]][0];
                float s = 0.f;
                #pragma unroll
                for (int k = 0; k < 8; ++k) {
                    uint4 v = pp[k];
                    s += __uint_as_float(v.x << 16) + __uint_as_float(v.x & 0xFFFF0000u);
                    s += __uint_as_float(v.y << 16) + __uint_as_float(v.y & 0xFFFF0000u);
                    s += __uint_as_float(v.z << 16) + __uint_as_float(v.z & 0xFFFF0000u);
                    s += __uint_as_float(v.w << 16) + __uint_as_float(v.w & 0xFFFF0000u);
                }
                an[q] = s + l1b2c;
            }
            float an0 = an[0], an1 = an[1], an2 = an[2], an3 = an[3];
            float g0 = S.g.gam[rw][ts0], g1 = S.g.gam[rw][ts1];
            float g2 = S.g.gam[rw][ts2], g3 = S.g.gam[rw][ts3];
            int   r0 = S.g.r[rw][ts0],   r1 = S.g.r[rw][ts1];
            int   r2 = S.g.r[rw][ts2],   r3 = S.g.r[rw][ts3];
            float alpha = 0.f;
            float* oa = out_alpha + b * Sn;
            for (int t = 0; t < Sn; ++t) {
                const int q = t >> 6, l = t & 63;
                float anv, g; int rr;
                if (q == 0)      { anv = rlanef(an0,l); g = rlanef(g0,l); rr = __builtin_amdgcn_readlane(r0,l); }
                else if (q == 1) { anv = rlanef(an1,l); g = rlanef(g1,l); rr = __builtin_amdgcn_readlane(r1,l); }
                else if (q == 2) { anv = rlanef(an2,l); g = rlanef(g2,l); rr = __builtin_amdgcn_readlane(r2,l); }
                else             { anv = rlanef(an3,l); g = rlanef(g3,l); rr = __builtin_amdgcn_readlane(r3,l); }
                bool cond = (alpha - g) >= 0.f;
                alpha = rr ? (cond ? anv : alpha) : (cond ? alpha : anv);
                if (j == 0) oa[t] = alpha;
            }
        }
    } else {
        // ===== C3 chain + contiguous forward-fill: one (row, t-third) =====
        const int fb = bid - GRUB;
        const int b  = fb / 3;
        const int th = fb - b * 3;
        if (tid < Sn) {
            S.f.gam[tid] = D_w[d_seq[b*Sn + tid]];
            S.f.r[tid]   = r_seq[b*Sn + tid];
            S.f.c3[tid]  = c3_seq[b*Sn + tid];
        }
        if (tid < 64) {
            const float4* row4 = (const float4*)(l2_w1 + (size_t)tid * 192);
            const float4* vc4  = (const float4*)v_c3;
            const float4* vd4  = (const float4*)v_d;
            const float4* q04  = (const float4*)R_w;
            const float4* q14  = (const float4*)(R_w + 64);
            float a2=0.f, b2=0.f, c0=0.f, c1=0.f;
            #pragma unroll 4
            for (int k = 0; k < 16; ++k) {
                float4 ra = row4[k], rb = row4[16+k], rc = row4[32+k];
                float4 vc = vc4[k], vd = vd4[k], q0 = q04[k], q1 = q14[k];
                a2 += ra.x*vc.x + ra.y*vc.y + ra.z*vc.z + ra.w*vc.w;
                b2 += rb.x*vd.x + rb.y*vd.y + rb.z*vd.z + rb.w*vd.w;
                c0 += rc.x*q0.x + rc.y*q0.y + rc.z*q0.z + rc.w*q0.w;
                c1 += rc.x*q1.x + rc.y*q1.y + rc.z*q1.z + rc.w*q1.w;
            }
            S.f.A[tid]  = a2;
            S.f.Bv[tid] = b2;
            S.f.C0[tid] = c0 + l2_b1[tid];
            S.f.C1[tid] = c1 + l2_b1[tid];
            S.f.W2[tid] = l2_w2[tid];
        }
        if (tid == 0) S.f.l2b2 = l2_b2[0];
        __syncthreads();
        if (tid < Sn) {
            int c = S.f.c3[tid];
            int s = -1;
            for (int u = tid + 1; u < Sn; ++u)
                if (S.f.c3[u] == c) { s = u; break; }
            S.f.succ[tid] = s;
            int rt = 1;
            for (int u = 0; u < tid; ++u)
                if (S.f.c3[u] == c) { rt = 0; break; }
            S.f.root[tid] = rt;
        }
        __syncthreads();
        {   // chain walk, 16-lane groups
            const int g  = tid >> 4;
            const int l  = tid & 15;
            const int j0 = l * 4;
            float A0=S.f.A[j0],  A1=S.f.A[j0+1],  A2=S.f.A[j0+2],  A3=S.f.A[j0+3];
            float B0=S.f.Bv[j0], B1=S.f.Bv[j0+1], B2=S.f.Bv[j0+2], B3=S.f.Bv[j0+3];
            float C00=S.f.C0[j0],C01=S.f.C0[j0+1],C02=S.f.C0[j0+2],C03=S.f.C0[j0+3];
            float C10=S.f.C1[j0],C11=S.f.C1[j0+1],C12=S.f.C1[j0+2],C13=S.f.C1[j0+3];
            float W0=S.f.W2[j0], W1=S.f.W2[j0+1], W2v=S.f.W2[j0+2],W3=S.f.W2[j0+3];
            float l2b2 = S.f.l2b2;
            for (int t0 = g; t0 < Sn; t0 += 16) {
                if (!S.f.root[t0]) continue;
                float beta = 0.f;
                int t = t0;
                while (t >= 0) {
                    float gam = S.f.gam[t];
                    int   r   = S.f.r[t];
                    float s = W0*fmaxf(A0*beta + B0*gam + (r ? C10 : C00), 0.f)
                            + W1*fmaxf(A1*beta + B1*gam + (r ? C11 : C01), 0.f)
                            + W2v*fmaxf(A2*beta + B2*gam + (r ? C12 : C02), 0.f)
                            + W3*fmaxf(A3*beta + B3*gam + (r ? C13 : C03), 0.f);
                    s += __shfl_xor(s, 1, 16);
                    s += __shfl_xor(s, 2, 16);
                    s += __shfl_xor(s, 4, 16);
                    s += __shfl_xor(s, 8, 16);
                    beta = s + l2b2;
                    if (l == 0) S.f.val[t] = beta;
                    t = S.f.succ[t];
                }
            }
        }
        __syncthreads();
        // forward-fill third: rows [t0, t1) x 16KB, contiguous stream, nt stores
        const int t0 = (th == 0) ? 0 : (th == 1 ? 67 : 134);
        const int t1 = (th == 0) ? 67 : (th == 1 ? 134 : 200);
        const int cA = tid*4, cB = 1024 + tid*4, cC = 2048 + tid*4, cD = 3072 + tid*4;
        float4 qA = make_float4(0.f,0.f,0.f,0.f), qB = qA, qC = qA, qD = qA;
        for (int t = 0; t < t0; ++t) {          // pre-scan (no stores)
            int cc = S.f.c3[t]; float v = S.f.val[t];
            UPD(qA, cA) UPD(qB, cB) UPD(qC, cC) UPD(qD, cD)
        }
        float* rowp = out_c3 + (size_t)b * Sn * NC3n + (size_t)t0 * NC3n;
        const bool doD = (tid < 232);
        for (int t = t0; t < t1; ++t) {
            int cc = S.f.c3[t]; float v = S.f.val[t];
            UPD(qA, cA) UPD(qB, cB) UPD(qC, cC) UPD(qD, cD)
            nt_store4(rowp + cA, qA);
            nt_store4(rowp + cB, qB);
            nt_store4(rowp + cC, qC);
            if (doD) nt_store4(rowp + cD, qD);
            rowp += NC3n;
        }
    }
}

extern "C" void kernel_launch(void* const* d_in, const int* in_sizes, int n_in,
                              void* d_out, int out_size, void* d_ws, size_t ws_size,
                              hipStream_t stream)
{
    const int*   c3_seq = (const int*)  d_in[0];
    const int*   d_seq  = (const int*)  d_in[1];
    const int*   r_seq  = (const int*)  d_in[2];
    const float* v_c3   = (const float*)d_in[3];
    const float* D_w    = (const float*)d_in[4];
    const float* v_d    = (const float*)d_in[5];
    const float* R_w    = (const float*)d_in[6];
    const float* W_ih   = (const float*)d_in[7];
    const float* W_hh   = (const float*)d_in[8];
    const float* b_ih   = (const float*)d_in[9];
    const float* b_hh   = (const float*)d_in[10];
    const float* l1_w1  = (const float*)d_in[11];
    const float* l1_b1  = (const float*)d_in[12];
    const float* l1_w2  = (const float*)d_in[13];
    const float* l1_b2  = (const float*)d_in[14];
    const float* l2_w1  = (const float*)d_in[15];
    const float* l2_b1  = (const float*)d_in[16];
    const float* l2_w2  = (const float*)d_in[17];
    const float* l2_b2  = (const float*)d_in[18];

    float* out_alpha = (float*)d_out;
    float* out_h     = out_alpha + Bn*Sn;
    float* out_c3    = out_h + (size_t)Bn*Sn*64;

    fused12_kernel<<<GRUB + FILLB, 256, 0, stream>>>(
        c3_seq, d_seq, r_seq, v_c3, D_w, v_d, R_w, W_ih, W_hh, b_ih, b_hh,
        l1_w1, l1_b1, l1_w2, l1_b2, l2_w1, l2_b1, l2_w2, l2_b2,
        out_alpha, out_h, out_c3);
}